// Round 5
// baseline (63.351 us; speedup 1.0000x reference)
//
#include <hip/hip_runtime.h>

#define IN_F   4096
#define OUT_F  4096
#define BATCH  512
#define NCONN  64
#define OT     8      // output features per block (1 per 32-lane group)
#define BT     128    // batch elements per block
#define NTHR   256

typedef float f4 __attribute__((ext_vector_type(4)));   // native vector for NT stores

// ---------------- Kernel 1: transpose x (B, IN_F) -> xT (IN_F, B) ----------------
__global__ __launch_bounds__(256) void transpose_kernel(const float* __restrict__ x,
                                                        float* __restrict__ xT) {
    __shared__ float tile[64 * 68];          // logical [row=b][col=j], swizzled cols
    const int j0 = blockIdx.x * 64;          // feature dim
    const int b0 = blockIdx.y * 64;          // batch dim
    const int t  = threadIdx.x;
    const int c  = t & 15;                   // float4 index within 64
    const int r0 = t >> 4;                   // 0..15

#pragma unroll
    for (int it = 0; it < 4; ++it) {
        const int r  = r0 + it * 16;                        // batch row in tile
        const int pc = (4 * c) ^ (((r >> 2) & 7) << 2);     // swizzled col (16B-aligned)
        const float4 v = *reinterpret_cast<const float4*>(
            x + (size_t)(b0 + r) * IN_F + j0 + 4 * c);
        *reinterpret_cast<float4*>(&tile[r * 68 + pc]) = v;
    }
    __syncthreads();
#pragma unroll
    for (int it = 0; it < 4; ++it) {
        const int jj = r0 + it * 16;                        // feature row of xT
        float4 v;
        float* vv = reinterpret_cast<float*>(&v);
#pragma unroll
        for (int i = 0; i < 4; ++i) {
            const int rr   = 4 * c + i;                     // batch index
            const int pcol = jj ^ (((rr >> 2) & 7) << 2);
            vv[i] = tile[rr * 68 + pcol];
        }
        *reinterpret_cast<float4*>(xT + (size_t)(j0 + jj) * BATCH + b0 + 4 * c) = v;
    }
}

// ---------------- Kernel 2: (OT x BT) tile gather + reduce ----------------
__global__ __launch_bounds__(NTHR) void agg_kernel(const float* __restrict__ xT,
                                                   const int* __restrict__ conn,
                                                   const int* __restrict__ opidx,
                                                   float* __restrict__ out) {
    // grid = 512 o-tiles * 4 b-tiles = 2048 blocks -> 8 blocks/CU, 32 waves/CU.
    // XCD partition (HW round-robins bid across 8 XCDs): XCD i owns b-tile
    // (i>>1) and o-tiles ((i&1)*256 + 0..255). Per-XCD xT footprint =
    // 4096 cols * 512 B = 2 MB < 4 MB L2 -> gathers are L2 hits after warmup.
    const int bid = blockIdx.x;
    const int xcd = bid & 7;
    const int ot  = ((xcd & 1) << 8) | (bid >> 3);   // 0..511
    const int bt  = xcd >> 1;                        // 0..3
    const int o0  = ot * OT;
    const int b0  = bt * BT;
    const int tid = threadIdx.x;

    __shared__ int   cs[OT][NCONN];          // 2 KB
    __shared__ int   ops[OT];
    __shared__ float stage[3][OT][BT + 4];   // ~12.4 KB: sum, max, min

    for (int i = tid; i < OT * NCONN; i += NTHR)
        (&cs[0][0])[i] = conn[o0 * NCONN + i];
    if (tid < OT) ops[tid] = opidx[o0 + tid];
    __syncthreads();

    const int lane = tid & 31;   // 32 lanes cover BT=128 as float4
    const int grp  = tid >> 5;   // 8 groups of 32 threads, 1 o each
    const int bb   = lane * 4;
    const float* __restrict__ xbase = xT + b0 + bb;
    const int* __restrict__ crow = cs[grp];

    float4 s  = make_float4(0.f, 0.f, 0.f, 0.f);
    float4 mx = make_float4(-__builtin_inff(), -__builtin_inff(),
                            -__builtin_inff(), -__builtin_inff());
    float4 mn = make_float4(__builtin_inff(), __builtin_inff(),
                            __builtin_inff(), __builtin_inff());

#pragma unroll 16
    for (int k = 0; k < NCONN; ++k) {
        const float4 a = *reinterpret_cast<const float4*>(xbase + crow[k] * BATCH);
        s.x += a.x;  s.y += a.y;  s.z += a.z;  s.w += a.w;
        mx.x = fmaxf(mx.x, a.x); mx.y = fmaxf(mx.y, a.y);
        mx.z = fmaxf(mx.z, a.z); mx.w = fmaxf(mx.w, a.w);
        mn.x = fminf(mn.x, a.x); mn.y = fminf(mn.y, a.y);
        mn.z = fminf(mn.z, a.z); mn.w = fminf(mn.w, a.w);
    }

    *reinterpret_cast<float4*>(&stage[0][grp][bb]) = s;
    *reinterpret_cast<float4*>(&stage[1][grp][bb]) = mx;
    *reinterpret_cast<float4*>(&stage[2][grp][bb]) = mn;
    __syncthreads();

    // ---- coalesced nontemporal write-out: float4 lines along o ----
    float* __restrict__ fwd  = out;                          // (B, OUT_F)
    float* __restrict__ outp = out + (size_t)BATCH * OUT_F;  // (B, 4, OUT_F)

    // OT*BT = 1024 outputs per stat = 256 float4 rows; 256 threads, 1 iter.
    {
        const int idx = tid;               // 0..255
        const int b   = idx >> 1;          // 0..127
        const int olb = (idx & 1) * 4;     // 0 or 4

        float sm[4], xm[4], nm[4], mean[4], fw[4];
#pragma unroll
        for (int i = 0; i < 4; ++i) {
            sm[i]   = stage[0][olb + i][b];
            xm[i]   = stage[1][olb + i][b];
            nm[i]   = stage[2][olb + i][b];
            mean[i] = sm[i] * 0.015625f;
            const int op = ops[olb + i];
            fw[i] = (op == 0) ? mean[i] : (op == 1) ? sm[i] : (op == 2) ? xm[i] : nm[i];
        }

        const size_t rowF = (size_t)(b0 + b) * OUT_F + o0 + olb;
        const size_t rowO = (size_t)(b0 + b) * (4 * OUT_F) + o0 + olb;
        __builtin_nontemporal_store((f4){fw[0], fw[1], fw[2], fw[3]},
                                    reinterpret_cast<f4*>(fwd + rowF));
        __builtin_nontemporal_store((f4){mean[0], mean[1], mean[2], mean[3]},
                                    reinterpret_cast<f4*>(outp + rowO));
        __builtin_nontemporal_store((f4){sm[0], sm[1], sm[2], sm[3]},
                                    reinterpret_cast<f4*>(outp + rowO + OUT_F));
        __builtin_nontemporal_store((f4){xm[0], xm[1], xm[2], xm[3]},
                                    reinterpret_cast<f4*>(outp + rowO + 2 * OUT_F));
        __builtin_nontemporal_store((f4){nm[0], nm[1], nm[2], nm[3]},
                                    reinterpret_cast<f4*>(outp + rowO + 3 * OUT_F));
    }
}

extern "C" void kernel_launch(void* const* d_in, const int* in_sizes, int n_in,
                              void* d_out, int out_size, void* d_ws, size_t ws_size,
                              hipStream_t stream) {
    const float* x     = (const float*)d_in[0];
    const int*   conn  = (const int*)d_in[1];
    const int*   opidx = (const int*)d_in[2];
    float*       out   = (float*)d_out;
    float*       xT    = (float*)d_ws;   // IN_F * BATCH floats = 8 MiB

    dim3 tg(IN_F / 64, BATCH / 64);      // 64 x 8 = 512 blocks
    transpose_kernel<<<tg, 256, 0, stream>>>(x, xT);

    const int nblocks = (OUT_F / OT) * (BATCH / BT);  // 2048
    agg_kernel<<<nblocks, NTHR, 0, stream>>>(xT, conn, opidx, out);
}

// Round 6
// 32.519 us; speedup vs baseline: 1.9482x; 1.9482x over previous
//
#include <hip/hip_runtime.h>

#define IN_F   4096
#define OUT_F  4096
#define BATCH  512
#define NCONN  64
#define OT     16     // output features per block
#define BT     128    // batch elements per block
#define NTHR   256

typedef float    f4 __attribute__((ext_vector_type(4)));   // NT stores
typedef _Float16 h4 __attribute__((ext_vector_type(4)));
typedef _Float16 h8 __attribute__((ext_vector_type(8)));

// ---------------- Kernel 1: transpose+cvt x (B, IN_F) f32 -> xTh (IN_F, B) fp16 ----
__global__ __launch_bounds__(256) void transpose_kernel(const float* __restrict__ x,
                                                        _Float16* __restrict__ xTh) {
    __shared__ float tile[64 * 68];          // logical [row=b][col=j], swizzled cols
    const int j0 = blockIdx.x * 64;          // feature dim
    const int b0 = blockIdx.y * 64;          // batch dim
    const int t  = threadIdx.x;
    const int c  = t & 15;                   // float4 index within 64
    const int r0 = t >> 4;                   // 0..15

#pragma unroll
    for (int it = 0; it < 4; ++it) {
        const int r  = r0 + it * 16;                        // batch row in tile
        const int pc = (4 * c) ^ (((r >> 2) & 7) << 2);     // swizzled col (16B-aligned)
        const float4 v = *reinterpret_cast<const float4*>(
            x + (size_t)(b0 + r) * IN_F + j0 + 4 * c);
        *reinterpret_cast<float4*>(&tile[r * 68 + pc]) = v;
    }
    __syncthreads();
#pragma unroll
    for (int it = 0; it < 4; ++it) {
        const int jj = r0 + it * 16;                        // feature row of xTh
        h4 v;
#pragma unroll
        for (int i = 0; i < 4; ++i) {
            const int rr   = 4 * c + i;                     // batch index
            const int pcol = jj ^ (((rr >> 2) & 7) << 2);
            v[i] = (_Float16)tile[rr * 68 + pcol];
        }
        *reinterpret_cast<h4*>(xTh + (size_t)(j0 + jj) * BATCH + b0 + 4 * c) = v;
    }
}

// ---------------- Kernel 2: (OT x BT) tile fp16 gather + f32 reduce ----------------
__global__ __launch_bounds__(NTHR) void agg_kernel(const _Float16* __restrict__ xTh,
                                                   const int* __restrict__ conn,
                                                   const int* __restrict__ opidx,
                                                   float* __restrict__ out) {
    // grid = 256 o-tiles * 4 b-tiles = 1024 blocks, 4/CU resident.
    // XCD partition: XCD i owns b-tile (i>>1), o-tiles ((i&1)*128 + 0..127).
    // Per-XCD xTh footprint = 4096 cols * 256 B = 1 MB << 4 MB L2.
    const int bid = blockIdx.x;
    const int xcd = bid & 7;
    const int ot  = ((xcd & 1) << 7) | (bid >> 3);   // 0..255
    const int bt  = xcd >> 1;                        // 0..3
    const int o0  = ot * OT;
    const int b0  = bt * BT;
    const int tid = threadIdx.x;

    __shared__ int   cs[OT][NCONN];          // 4 KB
    __shared__ int   ops[OT];
    __shared__ float stage[3][OT][BT + 4];   // ~24.8 KB: sum, max, min

    for (int i = tid; i < OT * NCONN; i += NTHR)
        (&cs[0][0])[i] = conn[o0 * NCONN + i];
    if (tid < OT) ops[tid] = opidx[o0 + tid];
    __syncthreads();

    const int lane = tid & 15;   // 16 lanes cover BT=128 as half8 (16 B each)
    const int grp  = tid >> 4;   // 16 groups of 16 threads, 1 o each
    const int bb   = lane * 8;
    const _Float16* __restrict__ xbase = xTh + b0 + bb;
    const int* __restrict__ crow = cs[grp];

    float s[8], mx[8], mn[8];
#pragma unroll
    for (int i = 0; i < 8; ++i) {
        s[i]  = 0.f;
        mx[i] = -__builtin_inff();
        mn[i] =  __builtin_inff();
    }

#pragma unroll 16
    for (int k = 0; k < NCONN; ++k) {
        const h8 a = *reinterpret_cast<const h8*>(xbase + crow[k] * BATCH);
#pragma unroll
        for (int i = 0; i < 8; ++i) {
            const float f = (float)a[i];
            s[i] += f;
            mx[i] = fmaxf(mx[i], f);
            mn[i] = fminf(mn[i], f);
        }
    }

    *reinterpret_cast<float4*>(&stage[0][grp][bb])     = make_float4(s[0], s[1], s[2], s[3]);
    *reinterpret_cast<float4*>(&stage[0][grp][bb + 4]) = make_float4(s[4], s[5], s[6], s[7]);
    *reinterpret_cast<float4*>(&stage[1][grp][bb])     = make_float4(mx[0], mx[1], mx[2], mx[3]);
    *reinterpret_cast<float4*>(&stage[1][grp][bb + 4]) = make_float4(mx[4], mx[5], mx[6], mx[7]);
    *reinterpret_cast<float4*>(&stage[2][grp][bb])     = make_float4(mn[0], mn[1], mn[2], mn[3]);
    *reinterpret_cast<float4*>(&stage[2][grp][bb + 4]) = make_float4(mn[4], mn[5], mn[6], mn[7]);
    __syncthreads();

    // ---- coalesced nontemporal write-out: full 64 B lines along o ----
    float* __restrict__ fwd  = out;                          // (B, OUT_F)
    float* __restrict__ outp = out + (size_t)BATCH * OUT_F;  // (B, 4, OUT_F)

#pragma unroll
    for (int it = 0; it < 2; ++it) {
        const int idx = it * NTHR + tid;   // 0..511
        const int b   = idx >> 2;          // 0..127
        const int olb = (idx & 3) * 4;     // 0,4,8,12

        float sm[4], xm[4], nm[4], mean[4], fw[4];
#pragma unroll
        for (int i = 0; i < 4; ++i) {
            sm[i]   = stage[0][olb + i][b];
            xm[i]   = stage[1][olb + i][b];
            nm[i]   = stage[2][olb + i][b];
            mean[i] = sm[i] * 0.015625f;
            const int op = ops[olb + i];
            fw[i] = (op == 0) ? mean[i] : (op == 1) ? sm[i] : (op == 2) ? xm[i] : nm[i];
        }

        const size_t rowF = (size_t)(b0 + b) * OUT_F + o0 + olb;
        const size_t rowO = (size_t)(b0 + b) * (4 * OUT_F) + o0 + olb;
        __builtin_nontemporal_store((f4){fw[0], fw[1], fw[2], fw[3]},
                                    reinterpret_cast<f4*>(fwd + rowF));
        __builtin_nontemporal_store((f4){mean[0], mean[1], mean[2], mean[3]},
                                    reinterpret_cast<f4*>(outp + rowO));
        __builtin_nontemporal_store((f4){sm[0], sm[1], sm[2], sm[3]},
                                    reinterpret_cast<f4*>(outp + rowO + OUT_F));
        __builtin_nontemporal_store((f4){xm[0], xm[1], xm[2], xm[3]},
                                    reinterpret_cast<f4*>(outp + rowO + 2 * OUT_F));
        __builtin_nontemporal_store((f4){nm[0], nm[1], nm[2], nm[3]},
                                    reinterpret_cast<f4*>(outp + rowO + 3 * OUT_F));
    }
}

extern "C" void kernel_launch(void* const* d_in, const int* in_sizes, int n_in,
                              void* d_out, int out_size, void* d_ws, size_t ws_size,
                              hipStream_t stream) {
    const float* x     = (const float*)d_in[0];
    const int*   conn  = (const int*)d_in[1];
    const int*   opidx = (const int*)d_in[2];
    float*       out   = (float*)d_out;
    _Float16*    xTh   = (_Float16*)d_ws;   // IN_F * BATCH fp16 = 4 MiB

    dim3 tg(IN_F / 64, BATCH / 64);      // 64 x 8 = 512 blocks
    transpose_kernel<<<tg, 256, 0, stream>>>(x, xTh);

    const int nblocks = (OUT_F / OT) * (BATCH / BT);  // 1024
    agg_kernel<<<nblocks, NTHR, 0, stream>>>(xTh, conn, opidx, out);
}